// Round 4
// baseline (341.488 us; speedup 1.0000x reference)
//
#include <hip/hip_runtime.h>
#include <hip/hip_bf16.h>
#include <math.h>

#define B 32
#define P 100
#define N 1000
#define D 128

constexpr float SQRT_D_INV = 1.0f / 11.313708498984761f;
constexpr float CLIPV = 10.0f;

__device__ __forceinline__ void fma4(float4& a, float s, const float4& b) {
    a.x = fmaf(s, b.x, a.x);
    a.y = fmaf(s, b.y, a.y);
    a.z = fmaf(s, b.z, a.z);
    a.w = fmaf(s, b.w, a.w);
}

// ---------------------------------------------------------------------------
// K0: transpose Wk, Wv (128x128) so kv_kernel reads coalesced.
// ---------------------------------------------------------------------------
__global__ void transpose_w(const float* __restrict__ Wk,
                            const float* __restrict__ Wv,
                            float* __restrict__ wkT,
                            float* __restrict__ wvT) {
    const int e = blockIdx.x;
    const int d = threadIdx.x;
    wkT[e * D + d] = Wk[d * D + e];
    wvT[e * D + d] = Wv[d * D + e];
}

// ---------------------------------------------------------------------------
// K1: ek = exp(nodes @ WkT), ekv = ek * (nodes @ WvT)
// block 256 threads = 8 row-lanes x 32 d-quads; R1=32 rows/block.
// ---------------------------------------------------------------------------
#define R1 32
__global__ __launch_bounds__(256) void kv_kernel(const float* __restrict__ nodes,
                          const float* __restrict__ wkT,
                          const float* __restrict__ wvT,
                          float* __restrict__ ek,
                          float* __restrict__ ekv) {
    __shared__ float sh[R1][D];
    const int t = threadIdx.x;
    const int dq = t & 31;
    const int rl = t >> 5;
    const long row0 = (long)blockIdx.x * R1;

    const float4* src = (const float4*)(nodes + row0 * D);
    float4* dst = (float4*)(&sh[0][0]);
    #pragma unroll
    for (int i = 0; i < (R1 * D / 4) / 256; ++i)
        dst[t + i * 256] = src[t + i * 256];
    __syncthreads();

    float4 ka[4], va[4];
    #pragma unroll
    for (int rr = 0; rr < 4; ++rr) {
        ka[rr] = make_float4(0.f, 0.f, 0.f, 0.f);
        va[rr] = make_float4(0.f, 0.f, 0.f, 0.f);
    }

    for (int e0 = 0; e0 < D; e0 += 4) {
        float4 wk4[4], wv4[4];
        #pragma unroll
        for (int ee = 0; ee < 4; ++ee) {
            wk4[ee] = *(const float4*)(wkT + (e0 + ee) * D + dq * 4);
            wv4[ee] = *(const float4*)(wvT + (e0 + ee) * D + dq * 4);
        }
        #pragma unroll
        for (int rr = 0; rr < 4; ++rr) {
            float4 s4 = *(const float4*)(&sh[rl * 4 + rr][e0]);
            fma4(ka[rr], s4.x, wk4[0]); fma4(ka[rr], s4.y, wk4[1]);
            fma4(ka[rr], s4.z, wk4[2]); fma4(ka[rr], s4.w, wk4[3]);
            fma4(va[rr], s4.x, wv4[0]); fma4(va[rr], s4.y, wv4[1]);
            fma4(va[rr], s4.z, wv4[2]); fma4(va[rr], s4.w, wv4[3]);
        }
    }

    #pragma unroll
    for (int rr = 0; rr < 4; ++rr) {
        long row = row0 + rl * 4 + rr;
        float4 e4;
        e4.x = __expf(ka[rr].x); e4.y = __expf(ka[rr].y);
        e4.z = __expf(ka[rr].z); e4.w = __expf(ka[rr].w);
        float4 ev;
        ev.x = e4.x * va[rr].x; ev.y = e4.y * va[rr].y;
        ev.z = e4.z * va[rr].z; ev.w = e4.w * va[rr].w;
        *(float4*)(ek + row * D + dq * 4) = e4;
        *(float4*)(ekv + row * D + dq * 4) = ev;
    }
}

// ---------------------------------------------------------------------------
// K2: qsig = sigmoid(q1 @ Wqf^T + qlast @ Wql^T)
// ---------------------------------------------------------------------------
#define R2 16
__global__ void q_kernel(const float* __restrict__ q1,
                         const float* __restrict__ qlast,
                         const float* __restrict__ Wqf,
                         const float* __restrict__ Wql,
                         float* __restrict__ qsig) {
    __shared__ float sh1[R2][D];
    __shared__ float sh2[R2][D];
    const int t = threadIdx.x;
    const long row0 = (long)blockIdx.x * R2;

    const float4* s1 = (const float4*)(q1 + row0 * D);
    const float4* s2 = (const float4*)(qlast + row0 * D);
    float4* d1 = (float4*)(&sh1[0][0]);
    float4* d2 = (float4*)(&sh2[0][0]);
    #pragma unroll
    for (int i = 0; i < (R2 * D / 4) / 128; ++i) {
        d1[t + i * 128] = s1[t + i * 128];
        d2[t + i * 128] = s2[t + i * 128];
    }
    __syncthreads();

    float acc[R2];
    #pragma unroll
    for (int r = 0; r < R2; ++r) acc[r] = 0.f;

    const float* wf = Wqf + t * D;
    const float* wl = Wql + t * D;
    for (int e = 0; e < D; ++e) {
        float a = wf[e];
        float c = wl[e];
        #pragma unroll
        for (int r = 0; r < R2; ++r) {
            acc[r] = fmaf(sh1[r][e], a, acc[r]);
            acc[r] = fmaf(sh2[r][e], c, acc[r]);
        }
    }
    #pragma unroll
    for (int r = 0; r < R2; ++r)
        qsig[(row0 + r) * D + t] = 1.0f / (1.0f + __expf(-acc[r]));
}

// ---------------------------------------------------------------------------
// K3a: partial num/den over an n-chunk.
// block 128 threads = 32 d-quads (dq) x 4 p-lanes (pl); PT=20 p's per block.
// Each thread owns COMPLETE sums for its 5 p's x 4 d's (walks every n in
// the chunk) -- no cross-lane reduction needed.
// eb layout [n_local][p], row stride 20 floats (16B-aligned b128 reads).
// ---------------------------------------------------------------------------
#define PT 20
__global__ __launch_bounds__(128) void aft_part_kernel(
        const float* __restrict__ cur_dist,
        const float* __restrict__ ninf,
        const float* __restrict__ ek,
        const float* __restrict__ ekv,
        const float* __restrict__ log_scale,
        const float* __restrict__ aft_alpha,
        float* __restrict__ pnum,
        float* __restrict__ pden,
        int NC, int L) {
    __shared__ float eb[128][PT];
    const int t = threadIdx.x;
    const int dq = t & 31;
    const int pl = t >> 5;          // 0..3
    const int c  = blockIdx.x % NC;
    const int pt = (blockIdx.x / NC) % (P / PT);
    const int b  = blockIdx.x / (NC * (P / PT));
    const int p0 = pt * PT;
    const int n_begin = c * L;
    const int n_end = min(N, n_begin + L);
    const float lsA = log_scale[0] * aft_alpha[0];

    // num[r<4] -> p = pl*4+r ; num[4] -> p = 16+pl
    float4 num[5], den[5];
    #pragma unroll
    for (int i = 0; i < 5; ++i) {
        num[i] = make_float4(0.f, 0.f, 0.f, 0.f);
        den[i] = make_float4(0.f, 0.f, 0.f, 0.f);
    }

    for (int n0 = n_begin; n0 < n_end; n0 += 128) {
        const int lim = min(128, n_end - n0);
        __syncthreads();
        if (t < lim) {
            int n = n0 + t;
            #pragma unroll
            for (int i = 0; i < PT; ++i) {
                long idx = ((long)b * P + p0 + i) * N + n;
                eb[t][i] = __expf(fmaf(-lsA, cur_dist[idx], ninf[idx]));
            }
        }
        __syncthreads();
        for (int j = 0; j < lim; ++j) {
            long base = ((long)b * N + n0 + j) * D + dq * 4;
            float4 ekq = *(const float4*)(ek + base);
            float4 evq = *(const float4*)(ekv + base);
            float4 e4 = *(const float4*)(&eb[j][pl * 4]);
            float es = eb[j][16 + pl];
            fma4(num[0], e4.x, evq); fma4(den[0], e4.x, ekq);
            fma4(num[1], e4.y, evq); fma4(den[1], e4.y, ekq);
            fma4(num[2], e4.z, evq); fma4(den[2], e4.z, ekq);
            fma4(num[3], e4.w, evq); fma4(den[3], e4.w, ekq);
            fma4(num[4], es,   evq); fma4(den[4], es,   ekq);
        }
    }

    #pragma unroll
    for (int r = 0; r < 4; ++r) {
        int p = pl * 4 + r;
        long o = (((long)c * B + b) * P + p0 + p) * D + dq * 4;
        *(float4*)(pnum + o) = num[r];
        *(float4*)(pden + o) = den[r];
    }
    {
        int p = 16 + pl;
        long o = (((long)c * B + b) * P + p0 + p) * D + dq * 4;
        *(float4*)(pnum + o) = num[4];
        *(float4*)(pden + o) = den[4];
    }
}

// ---------------------------------------------------------------------------
// K3b: reduce chunks, aft = qsig * num / den.
// ---------------------------------------------------------------------------
__global__ void aft_reduce_kernel(const float* __restrict__ pnum,
                                  const float* __restrict__ pden,
                                  const float* __restrict__ qsig,
                                  float* __restrict__ aft,
                                  int NC) {
    const long i = (long)blockIdx.x * 256 + threadIdx.x;
    const long BPD = (long)B * P * D;
    float n = 0.f, d = 0.f;
    for (int c = 0; c < NC; ++c) {
        n += pnum[(long)c * BPD + i];
        d += pden[(long)c * BPD + i];
    }
    aft[i] = qsig[i] * n / d;
}

// ---------------------------------------------------------------------------
// K4: fused score + clip-tanh + softmax.
// block = (b, p-tile of PT2=5); 256 threads, each owns 4 n's (t + j*256).
// Each thread computes its dot products completely (e-loop in-thread).
// ---------------------------------------------------------------------------
#define PT2 5
#define NJ 4
__global__ __launch_bounds__(256) void score_kernel(
        const float* __restrict__ aft,
        const float* __restrict__ nodes,
        const float* __restrict__ cur_dist,
        const float* __restrict__ ninf,
        const float* __restrict__ log_scale,
        const float* __restrict__ dist_alpha,
        float* __restrict__ out) {
    __shared__ float red[4];
    __shared__ float bval;
    const int t = threadIdx.x;
    const int wid = t >> 6;
    const int pt = blockIdx.x % (P / PT2);
    const int b  = blockIdx.x / (P / PT2);
    const int p0 = pt * PT2;
    const float lsA = log_scale[0] * dist_alpha[0];
    const float* aftb = aft + ((long)b * P + p0) * D;

    int nn[NJ];
    const float* nrow[NJ];
    #pragma unroll
    for (int j = 0; j < NJ; ++j) {
        nn[j] = t + j * 256;
        int ncl = min(nn[j], N - 1);
        nrow[j] = nodes + ((long)b * N + ncl) * D;
    }

    float acc[NJ][PT2];
    #pragma unroll
    for (int j = 0; j < NJ; ++j)
        #pragma unroll
        for (int i = 0; i < PT2; ++i) acc[j][i] = 0.f;

    for (int e0 = 0; e0 < D; e0 += 4) {
        float4 x[NJ];
        #pragma unroll
        for (int j = 0; j < NJ; ++j) x[j] = *(const float4*)(nrow[j] + e0);
        #pragma unroll
        for (int i = 0; i < PT2; ++i) {
            float4 a4 = *(const float4*)(aftb + i * D + e0);
            #pragma unroll
            for (int j = 0; j < NJ; ++j) {
                acc[j][i] = fmaf(x[j].x, a4.x, acc[j][i]);
                acc[j][i] = fmaf(x[j].y, a4.y, acc[j][i]);
                acc[j][i] = fmaf(x[j].z, a4.z, acc[j][i]);
                acc[j][i] = fmaf(x[j].w, a4.w, acc[j][i]);
            }
        }
    }

    float sc[NJ][PT2];
    #pragma unroll
    for (int j = 0; j < NJ; ++j) {
        #pragma unroll
        for (int i = 0; i < PT2; ++i) {
            if (nn[j] < N) {
                long idx = ((long)b * P + p0 + i) * N + nn[j];
                float s = fmaf(acc[j][i], SQRT_D_INV, -lsA * cur_dist[idx]);
                float ax = fabsf(s);
                float r = 1.f - 2.f / (__expf(2.f * ax) + 1.f);
                sc[j][i] = CLIPV * copysignf(r, s) + ninf[idx];
            } else {
                sc[j][i] = -INFINITY;
            }
        }
    }

    #pragma unroll 1
    for (int i = 0; i < PT2; ++i) {
        float m = -INFINITY;
        #pragma unroll
        for (int j = 0; j < NJ; ++j) m = fmaxf(m, sc[j][i]);
        #pragma unroll
        for (int o = 1; o < 64; o <<= 1) m = fmaxf(m, __shfl_xor(m, o, 64));
        if ((t & 63) == 0) red[wid] = m;
        __syncthreads();
        if (t == 0) bval = fmaxf(fmaxf(red[0], red[1]), fmaxf(red[2], red[3]));
        __syncthreads();
        m = bval;

        float ssum = 0.f;
        #pragma unroll
        for (int j = 0; j < NJ; ++j) {
            float e = (sc[j][i] > -1e30f) ? __expf(sc[j][i] - m) : 0.f;
            sc[j][i] = e;
            ssum += e;
        }
        #pragma unroll
        for (int o = 1; o < 64; o <<= 1) ssum += __shfl_xor(ssum, o, 64);
        if ((t & 63) == 0) red[wid] = ssum;
        __syncthreads();
        if (t == 0) bval = red[0] + red[1] + red[2] + red[3];
        __syncthreads();
        float inv = 1.0f / bval;
        #pragma unroll
        for (int j = 0; j < NJ; ++j)
            if (nn[j] < N)
                out[((long)b * P + p0 + i) * N + nn[j]] = sc[j][i] * inv;
        __syncthreads();
    }
}

// ---------------------------------------------------------------------------
extern "C" void kernel_launch(void* const* d_in, const int* in_sizes, int n_in,
                              void* d_out, int out_size, void* d_ws, size_t ws_size,
                              hipStream_t stream) {
    const float* nodes      = (const float*)d_in[0];
    const float* q1         = (const float*)d_in[1];
    const float* qlast      = (const float*)d_in[2];
    const float* cur_dist   = (const float*)d_in[3];
    const float* ninf       = (const float*)d_in[4];
    const float* log_scale  = (const float*)d_in[5];
    const float* Wqf        = (const float*)d_in[6];
    const float* Wql        = (const float*)d_in[7];
    const float* Wk         = (const float*)d_in[8];
    const float* Wv         = (const float*)d_in[9];
    const float* dist_alpha = (const float*)d_in[10];
    const float* aft_alpha  = (const float*)d_in[11];
    float* out = (float*)d_out;

    const long BND = (long)B * N * D;
    const long BPD = (long)B * P * D;
    const long W2  = (long)D * D;

    float* ws   = (float*)d_ws;
    float* ek   = ws;
    float* ekv  = ek + BND;
    float* qsig = ekv + BND;
    float* aft  = qsig + BPD;
    float* wkT  = aft + BPD;
    float* wvT  = wkT + W2;
    float* pnum = wvT + W2;

    long avail = (long)(ws_size / 4) - (2 * BND + 2 * BPD + 2 * W2);
    int NC = (int)(avail / (2 * BPD));
    if (NC < 1) NC = 1;
    if (NC > 10) NC = 10;
    int L = (N + NC - 1) / NC;
    float* pden = pnum + (long)NC * BPD;

    transpose_w<<<D, D, 0, stream>>>(Wk, Wv, wkT, wvT);
    kv_kernel<<<(B * N) / R1, 256, 0, stream>>>(nodes, wkT, wvT, ek, ekv);
    q_kernel<<<(B * P) / R2, 128, 0, stream>>>(q1, qlast, Wqf, Wql, qsig);
    aft_part_kernel<<<B * (P / PT) * NC, 128, 0, stream>>>(
        cur_dist, ninf, ek, ekv, log_scale, aft_alpha, pnum, pden, NC, L);
    aft_reduce_kernel<<<(int)(BPD / 256), 256, 0, stream>>>(pnum, pden, qsig, aft, NC);
    score_kernel<<<B * (P / PT2), 256, 0, stream>>>(
        aft, nodes, cur_dist, ninf, log_scale, dist_alpha, out);
}

// Round 5
// 304.594 us; speedup vs baseline: 1.1211x; 1.1211x over previous
//
#include <hip/hip_runtime.h>
#include <hip/hip_bf16.h>
#include <math.h>

#define B 32
#define P 100
#define N 1000
#define D 128

constexpr float SQRT_D_INV = 1.0f / 11.313708498984761f;
constexpr float CLIPV = 10.0f;

__device__ __forceinline__ void fma4(float4& a, float s, const float4& b) {
    a.x = fmaf(s, b.x, a.x);
    a.y = fmaf(s, b.y, a.y);
    a.z = fmaf(s, b.z, a.z);
    a.w = fmaf(s, b.w, a.w);
}

// ---------------------------------------------------------------------------
// K0: transpose Wk, Wv (128x128) so kv_kernel reads coalesced.
// ---------------------------------------------------------------------------
__global__ void transpose_w(const float* __restrict__ Wk,
                            const float* __restrict__ Wv,
                            float* __restrict__ wkT,
                            float* __restrict__ wvT) {
    const int e = blockIdx.x;
    const int d = threadIdx.x;
    wkT[e * D + d] = Wk[d * D + e];
    wvT[e * D + d] = Wv[d * D + e];
}

// ---------------------------------------------------------------------------
// K0b: transpose nodes -> nodesT[b][e][n]  (so score streams along n).
// block = (b, n-tile of 64); 256 threads. LDS pad +1 -> conflict-free column reads.
// ---------------------------------------------------------------------------
#define TT 64
__global__ __launch_bounds__(256) void transpose_nodes(
        const float* __restrict__ nodes, float* __restrict__ nodesT) {
    __shared__ float sh[TT][D + 1];
    const int ntiles = (N + TT - 1) / TT;   // 16
    const int b  = blockIdx.x / ntiles;
    const int n0 = (blockIdx.x % ntiles) * TT;
    const int t = threadIdx.x;
    const int rows = min(TT, N - n0);

    const float4* src = (const float4*)(nodes + ((long)b * N + n0) * D);
    for (int i = t; i < rows * (D / 4); i += 256) {
        int r = i >> 5, c = i & 31;
        float4 v = src[(long)r * (D / 4) + c];
        sh[r][c * 4 + 0] = v.x; sh[r][c * 4 + 1] = v.y;
        sh[r][c * 4 + 2] = v.z; sh[r][c * 4 + 3] = v.w;
    }
    __syncthreads();

    const int nl = t & 63;      // lane along n (coalesced writes)
    const int eg = t >> 6;      // 4 e-groups of 32
    if (nl < rows) {
        #pragma unroll
        for (int k = 0; k < 32; ++k) {
            int e = eg * 32 + k;
            nodesT[((long)b * D + e) * N + n0 + nl] = sh[nl][e];
        }
    }
}

// ---------------------------------------------------------------------------
// K1: ek = exp(nodes @ WkT), ekv = ek * (nodes @ WvT)
// ---------------------------------------------------------------------------
#define R1 32
__global__ __launch_bounds__(256) void kv_kernel(const float* __restrict__ nodes,
                          const float* __restrict__ wkT,
                          const float* __restrict__ wvT,
                          float* __restrict__ ek,
                          float* __restrict__ ekv) {
    __shared__ float sh[R1][D];
    const int t = threadIdx.x;
    const int dq = t & 31;
    const int rl = t >> 5;
    const long row0 = (long)blockIdx.x * R1;

    const float4* src = (const float4*)(nodes + row0 * D);
    float4* dst = (float4*)(&sh[0][0]);
    #pragma unroll
    for (int i = 0; i < (R1 * D / 4) / 256; ++i)
        dst[t + i * 256] = src[t + i * 256];
    __syncthreads();

    float4 ka[4], va[4];
    #pragma unroll
    for (int rr = 0; rr < 4; ++rr) {
        ka[rr] = make_float4(0.f, 0.f, 0.f, 0.f);
        va[rr] = make_float4(0.f, 0.f, 0.f, 0.f);
    }

    for (int e0 = 0; e0 < D; e0 += 4) {
        float4 wk4[4], wv4[4];
        #pragma unroll
        for (int ee = 0; ee < 4; ++ee) {
            wk4[ee] = *(const float4*)(wkT + (e0 + ee) * D + dq * 4);
            wv4[ee] = *(const float4*)(wvT + (e0 + ee) * D + dq * 4);
        }
        #pragma unroll
        for (int rr = 0; rr < 4; ++rr) {
            float4 s4 = *(const float4*)(&sh[rl * 4 + rr][e0]);
            fma4(ka[rr], s4.x, wk4[0]); fma4(ka[rr], s4.y, wk4[1]);
            fma4(ka[rr], s4.z, wk4[2]); fma4(ka[rr], s4.w, wk4[3]);
            fma4(va[rr], s4.x, wv4[0]); fma4(va[rr], s4.y, wv4[1]);
            fma4(va[rr], s4.z, wv4[2]); fma4(va[rr], s4.w, wv4[3]);
        }
    }

    #pragma unroll
    for (int rr = 0; rr < 4; ++rr) {
        long row = row0 + rl * 4 + rr;
        float4 e4;
        e4.x = __expf(ka[rr].x); e4.y = __expf(ka[rr].y);
        e4.z = __expf(ka[rr].z); e4.w = __expf(ka[rr].w);
        float4 ev;
        ev.x = e4.x * va[rr].x; ev.y = e4.y * va[rr].y;
        ev.z = e4.z * va[rr].z; ev.w = e4.w * va[rr].w;
        *(float4*)(ek + row * D + dq * 4) = e4;
        *(float4*)(ekv + row * D + dq * 4) = ev;
    }
}

// ---------------------------------------------------------------------------
// K2: qsig = sigmoid(q1 @ Wqf^T + qlast @ Wql^T)
// ---------------------------------------------------------------------------
#define R2 16
__global__ void q_kernel(const float* __restrict__ q1,
                         const float* __restrict__ qlast,
                         const float* __restrict__ Wqf,
                         const float* __restrict__ Wql,
                         float* __restrict__ qsig) {
    __shared__ float sh1[R2][D];
    __shared__ float sh2[R2][D];
    const int t = threadIdx.x;
    const long row0 = (long)blockIdx.x * R2;

    const float4* s1 = (const float4*)(q1 + row0 * D);
    const float4* s2 = (const float4*)(qlast + row0 * D);
    float4* d1 = (float4*)(&sh1[0][0]);
    float4* d2 = (float4*)(&sh2[0][0]);
    #pragma unroll
    for (int i = 0; i < (R2 * D / 4) / 128; ++i) {
        d1[t + i * 128] = s1[t + i * 128];
        d2[t + i * 128] = s2[t + i * 128];
    }
    __syncthreads();

    float acc[R2];
    #pragma unroll
    for (int r = 0; r < R2; ++r) acc[r] = 0.f;

    const float* wf = Wqf + t * D;
    const float* wl = Wql + t * D;
    for (int e = 0; e < D; ++e) {
        float a = wf[e];
        float c = wl[e];
        #pragma unroll
        for (int r = 0; r < R2; ++r) {
            acc[r] = fmaf(sh1[r][e], a, acc[r]);
            acc[r] = fmaf(sh2[r][e], c, acc[r]);
        }
    }
    #pragma unroll
    for (int r = 0; r < R2; ++r)
        qsig[(row0 + r) * D + t] = 1.0f / (1.0f + __expf(-acc[r]));
}

// ---------------------------------------------------------------------------
// K3a: partial num/den over an n-chunk (verified R4 structure).
// ---------------------------------------------------------------------------
#define PT 20
__global__ __launch_bounds__(128) void aft_part_kernel(
        const float* __restrict__ cur_dist,
        const float* __restrict__ ninf,
        const float* __restrict__ ek,
        const float* __restrict__ ekv,
        const float* __restrict__ log_scale,
        const float* __restrict__ aft_alpha,
        float* __restrict__ pnum,
        float* __restrict__ pden,
        int NC, int L) {
    __shared__ float eb[128][PT];
    const int t = threadIdx.x;
    const int dq = t & 31;
    const int pl = t >> 5;
    const int c  = blockIdx.x % NC;
    const int pt = (blockIdx.x / NC) % (P / PT);
    const int b  = blockIdx.x / (NC * (P / PT));
    const int p0 = pt * PT;
    const int n_begin = c * L;
    const int n_end = min(N, n_begin + L);
    const float lsA = log_scale[0] * aft_alpha[0];

    float4 num[5], den[5];
    #pragma unroll
    for (int i = 0; i < 5; ++i) {
        num[i] = make_float4(0.f, 0.f, 0.f, 0.f);
        den[i] = make_float4(0.f, 0.f, 0.f, 0.f);
    }

    for (int n0 = n_begin; n0 < n_end; n0 += 128) {
        const int lim = min(128, n_end - n0);
        __syncthreads();
        if (t < lim) {
            int n = n0 + t;
            #pragma unroll
            for (int i = 0; i < PT; ++i) {
                long idx = ((long)b * P + p0 + i) * N + n;
                eb[t][i] = __expf(fmaf(-lsA, cur_dist[idx], ninf[idx]));
            }
        }
        __syncthreads();
        for (int j = 0; j < lim; ++j) {
            long base = ((long)b * N + n0 + j) * D + dq * 4;
            float4 ekq = *(const float4*)(ek + base);
            float4 evq = *(const float4*)(ekv + base);
            float4 e4 = *(const float4*)(&eb[j][pl * 4]);
            float es = eb[j][16 + pl];
            fma4(num[0], e4.x, evq); fma4(den[0], e4.x, ekq);
            fma4(num[1], e4.y, evq); fma4(den[1], e4.y, ekq);
            fma4(num[2], e4.z, evq); fma4(den[2], e4.z, ekq);
            fma4(num[3], e4.w, evq); fma4(den[3], e4.w, ekq);
            fma4(num[4], es,   evq); fma4(den[4], es,   ekq);
        }
    }

    #pragma unroll
    for (int r = 0; r < 4; ++r) {
        int p = pl * 4 + r;
        long o = (((long)c * B + b) * P + p0 + p) * D + dq * 4;
        *(float4*)(pnum + o) = num[r];
        *(float4*)(pden + o) = den[r];
    }
    {
        int p = 16 + pl;
        long o = (((long)c * B + b) * P + p0 + p) * D + dq * 4;
        *(float4*)(pnum + o) = num[4];
        *(float4*)(pden + o) = den[4];
    }
}

// ---------------------------------------------------------------------------
// K3b: reduce chunks, aft = qsig * num / den.
// ---------------------------------------------------------------------------
__global__ void aft_reduce_kernel(const float* __restrict__ pnum,
                                  const float* __restrict__ pden,
                                  const float* __restrict__ qsig,
                                  float* __restrict__ aft,
                                  int NC) {
    const long i = (long)blockIdx.x * 256 + threadIdx.x;
    const long BPD = (long)B * P * D;
    float n = 0.f, d = 0.f;
    for (int c = 0; c < NC; ++c) {
        n += pnum[(long)c * BPD + i];
        d += pden[(long)c * BPD + i];
    }
    aft[i] = qsig[i] * n / d;
}

// ---------------------------------------------------------------------------
// K4: fused score + clip-tanh + softmax, reading nodesT (coalesced along n).
// block = (b, p-tile of PT2=10); 512 threads, thread owns n = 2t, 2t+1.
// aft reads are block-uniform -> scalar loads.
// ---------------------------------------------------------------------------
#define PT2 10
__global__ __launch_bounds__(512) void score_kernel(
        const float* __restrict__ aft,
        const float* __restrict__ nodesT,
        const float* __restrict__ cur_dist,
        const float* __restrict__ ninf,
        const float* __restrict__ log_scale,
        const float* __restrict__ dist_alpha,
        float* __restrict__ out) {
    __shared__ float red[8];
    __shared__ float bval;
    const int t = threadIdx.x;
    const int wid = t >> 6;
    const int pt = blockIdx.x % (P / PT2);
    const int b  = blockIdx.x / (P / PT2);
    const int p0 = pt * PT2;
    const float lsA = log_scale[0] * dist_alpha[0];
    const float* aftb = aft + ((long)b * P + p0) * D;

    const int n0 = t * 2;                 // thread's pair of n's
    const bool act = (n0 < N);            // exactly 500 active threads
    const int ncl = act ? n0 : 0;
    const float* ntb = nodesT + (long)b * D * N;

    float2 acc[PT2];
    #pragma unroll
    for (int i = 0; i < PT2; ++i) acc[i] = make_float2(0.f, 0.f);

    for (int e0 = 0; e0 < D; e0 += 4) {
        float2 x[4];
        #pragma unroll
        for (int ee = 0; ee < 4; ++ee)
            x[ee] = *(const float2*)(ntb + (long)(e0 + ee) * N + ncl);
        #pragma unroll
        for (int i = 0; i < PT2; ++i) {
            float4 a4 = *(const float4*)(aftb + i * D + e0);   // uniform
            acc[i].x = fmaf(x[0].x, a4.x, acc[i].x);
            acc[i].x = fmaf(x[1].x, a4.y, acc[i].x);
            acc[i].x = fmaf(x[2].x, a4.z, acc[i].x);
            acc[i].x = fmaf(x[3].x, a4.w, acc[i].x);
            acc[i].y = fmaf(x[0].y, a4.x, acc[i].y);
            acc[i].y = fmaf(x[1].y, a4.y, acc[i].y);
            acc[i].y = fmaf(x[2].y, a4.z, acc[i].y);
            acc[i].y = fmaf(x[3].y, a4.w, acc[i].y);
        }
    }

    // clipped scores
    float2 sc[PT2];
    #pragma unroll
    for (int i = 0; i < PT2; ++i) {
        if (act) {
            long idx = ((long)b * P + p0 + i) * N + n0;
            float2 cd = *(const float2*)(cur_dist + idx);
            float2 nf = *(const float2*)(ninf + idx);
            float sx = fmaf(acc[i].x, SQRT_D_INV, -lsA * cd.x);
            float sy = fmaf(acc[i].y, SQRT_D_INV, -lsA * cd.y);
            float ax = fabsf(sx), ay = fabsf(sy);
            float rx = 1.f - 2.f / (__expf(2.f * ax) + 1.f);
            float ry = 1.f - 2.f / (__expf(2.f * ay) + 1.f);
            sc[i].x = CLIPV * copysignf(rx, sx) + nf.x;
            sc[i].y = CLIPV * copysignf(ry, sy) + nf.y;
        } else {
            sc[i].x = -INFINITY;
            sc[i].y = -INFINITY;
        }
    }

    // per-p softmax over n
    #pragma unroll 1
    for (int i = 0; i < PT2; ++i) {
        float m = fmaxf(sc[i].x, sc[i].y);
        #pragma unroll
        for (int o = 1; o < 64; o <<= 1) m = fmaxf(m, __shfl_xor(m, o, 64));
        if ((t & 63) == 0) red[wid] = m;
        __syncthreads();
        if (t == 0) {
            float mm = red[0];
            #pragma unroll
            for (int w = 1; w < 8; ++w) mm = fmaxf(mm, red[w]);
            bval = mm;
        }
        __syncthreads();
        m = bval;

        float ex = (sc[i].x > -1e30f) ? __expf(sc[i].x - m) : 0.f;
        float ey = (sc[i].y > -1e30f) ? __expf(sc[i].y - m) : 0.f;
        float ssum = ex + ey;
        #pragma unroll
        for (int o = 1; o < 64; o <<= 1) ssum += __shfl_xor(ssum, o, 64);
        if ((t & 63) == 0) red[wid] = ssum;
        __syncthreads();
        if (t == 0) {
            float ss = red[0];
            #pragma unroll
            for (int w = 1; w < 8; ++w) ss += red[w];
            bval = ss;
        }
        __syncthreads();
        float inv = 1.0f / bval;
        if (act) {
            long idx = ((long)b * P + p0 + i) * N + n0;
            float2 o2 = make_float2(ex * inv, ey * inv);
            *(float2*)(out + idx) = o2;
        }
        __syncthreads();
    }
}

// ---------------------------------------------------------------------------
extern "C" void kernel_launch(void* const* d_in, const int* in_sizes, int n_in,
                              void* d_out, int out_size, void* d_ws, size_t ws_size,
                              hipStream_t stream) {
    const float* nodes      = (const float*)d_in[0];
    const float* q1         = (const float*)d_in[1];
    const float* qlast      = (const float*)d_in[2];
    const float* cur_dist   = (const float*)d_in[3];
    const float* ninf       = (const float*)d_in[4];
    const float* log_scale  = (const float*)d_in[5];
    const float* Wqf        = (const float*)d_in[6];
    const float* Wql        = (const float*)d_in[7];
    const float* Wk         = (const float*)d_in[8];
    const float* Wv         = (const float*)d_in[9];
    const float* dist_alpha = (const float*)d_in[10];
    const float* aft_alpha  = (const float*)d_in[11];
    float* out = (float*)d_out;

    const long BND = (long)B * N * D;   // 4.096M floats (16.4 MB)
    const long BPD = (long)B * P * D;   // 0.41M floats
    const long W2  = (long)D * D;

    float* ws     = (float*)d_ws;
    float* ek     = ws;
    float* ekv    = ek + BND;
    float* qsig   = ekv + BND;
    float* aft    = qsig + BPD;
    float* wkT    = aft + BPD;
    float* wvT    = wkT + W2;
    float* nodesT = wvT + W2;            // BND
    float* pnum   = nodesT + BND;

    long avail = (long)(ws_size / 4) - (3 * BND + 2 * BPD + 2 * W2);
    int NC = (int)(avail / (2 * BPD));
    if (NC < 1) NC = 1;
    if (NC > 8) NC = 8;
    int L = (N + NC - 1) / NC;
    float* pden = pnum + (long)NC * BPD;

    transpose_w<<<D, D, 0, stream>>>(Wk, Wv, wkT, wvT);
    transpose_nodes<<<B * ((N + TT - 1) / TT), 256, 0, stream>>>(nodes, nodesT);
    kv_kernel<<<(B * N) / R1, 256, 0, stream>>>(nodes, wkT, wvT, ek, ekv);
    q_kernel<<<(B * P) / R2, 128, 0, stream>>>(q1, qlast, Wqf, Wql, qsig);
    aft_part_kernel<<<B * (P / PT) * NC, 128, 0, stream>>>(
        cur_dist, ninf, ek, ekv, log_scale, aft_alpha, pnum, pden, NC, L);
    aft_reduce_kernel<<<(int)(BPD / 256), 256, 0, stream>>>(pnum, pden, qsig, aft, NC);
    score_kernel<<<B * (P / PT2), 512, 0, stream>>>(
        aft, nodesT, cur_dist, ninf, log_scale, dist_alpha, out);
}

// Round 6
// 257.920 us; speedup vs baseline: 1.3240x; 1.1810x over previous
//
#include <hip/hip_runtime.h>
#include <hip/hip_bf16.h>
#include <math.h>

#define B 32
#define P 100
#define N 1000
#define D 128

constexpr float SQRT_D_INV = 1.0f / 11.313708498984761f;
constexpr float CLIPV = 10.0f;

__device__ __forceinline__ void fma4(float4& a, float s, const float4& b) {
    a.x = fmaf(s, b.x, a.x);
    a.y = fmaf(s, b.y, a.y);
    a.z = fmaf(s, b.z, a.z);
    a.w = fmaf(s, b.w, a.w);
}

// ---------------------------------------------------------------------------
// K0: transpose all 4 weight matrices (128x128) for coalesced streaming.
// ---------------------------------------------------------------------------
__global__ void transpose_w4(const float* __restrict__ Wk,
                             const float* __restrict__ Wv,
                             const float* __restrict__ Wqf,
                             const float* __restrict__ Wql,
                             float* __restrict__ wkT,
                             float* __restrict__ wvT,
                             float* __restrict__ wqfT,
                             float* __restrict__ wqlT) {
    const int e = blockIdx.x;
    const int d = threadIdx.x;
    wkT[e * D + d]  = Wk[d * D + e];
    wvT[e * D + d]  = Wv[d * D + e];
    wqfT[e * D + d] = Wqf[d * D + e];
    wqlT[e * D + d] = Wql[d * D + e];
}

// ---------------------------------------------------------------------------
// K0b: transpose nodes -> nodesT[b][e][n].
// ---------------------------------------------------------------------------
#define TT 64
__global__ __launch_bounds__(256) void transpose_nodes(
        const float* __restrict__ nodes, float* __restrict__ nodesT) {
    __shared__ float sh[TT][D + 1];
    const int ntiles = (N + TT - 1) / TT;
    const int b  = blockIdx.x / ntiles;
    const int n0 = (blockIdx.x % ntiles) * TT;
    const int t = threadIdx.x;
    const int rows = min(TT, N - n0);

    const float4* src = (const float4*)(nodes + ((long)b * N + n0) * D);
    for (int i = t; i < rows * (D / 4); i += 256) {
        int r = i >> 5, c = i & 31;
        float4 v = src[(long)r * (D / 4) + c];
        sh[r][c * 4 + 0] = v.x; sh[r][c * 4 + 1] = v.y;
        sh[r][c * 4 + 2] = v.z; sh[r][c * 4 + 3] = v.w;
    }
    __syncthreads();

    const int nl = t & 63;
    const int eg = t >> 6;
    if (nl < rows) {
        #pragma unroll
        for (int k = 0; k < 32; ++k) {
            int e = eg * 32 + k;
            nodesT[((long)b * D + e) * N + n0 + nl] = sh[nl][e];
        }
    }
}

// ---------------------------------------------------------------------------
// K1: ek = exp(nodes @ WkT), ekv = ek * (nodes @ WvT)
// ---------------------------------------------------------------------------
#define R1 32
__global__ __launch_bounds__(256, 2) void kv_kernel(
        const float* __restrict__ nodes,
        const float* __restrict__ wkT,
        const float* __restrict__ wvT,
        float* __restrict__ ek,
        float* __restrict__ ekv) {
    __shared__ float sh[R1][D];
    const int t = threadIdx.x;
    const int dq = t & 31;
    const int rl = t >> 5;
    const long row0 = (long)blockIdx.x * R1;

    const float4* src = (const float4*)(nodes + row0 * D);
    float4* dst = (float4*)(&sh[0][0]);
    #pragma unroll
    for (int i = 0; i < (R1 * D / 4) / 256; ++i)
        dst[t + i * 256] = src[t + i * 256];
    __syncthreads();

    float4 ka[4], va[4];
    #pragma unroll
    for (int rr = 0; rr < 4; ++rr) {
        ka[rr] = make_float4(0.f, 0.f, 0.f, 0.f);
        va[rr] = make_float4(0.f, 0.f, 0.f, 0.f);
    }

    const float* wkp = wkT + dq * 4;
    const float* wvp = wvT + dq * 4;
    #pragma unroll 4
    for (int e0 = 0; e0 < D; e0 += 4) {
        float4 wk4[4], wv4[4];
        #pragma unroll
        for (int ee = 0; ee < 4; ++ee) {
            wk4[ee] = *(const float4*)(wkp + (e0 + ee) * D);
            wv4[ee] = *(const float4*)(wvp + (e0 + ee) * D);
        }
        #pragma unroll
        for (int rr = 0; rr < 4; ++rr) {
            float4 s4 = *(const float4*)(&sh[rl * 4 + rr][e0]);
            fma4(ka[rr], s4.x, wk4[0]); fma4(ka[rr], s4.y, wk4[1]);
            fma4(ka[rr], s4.z, wk4[2]); fma4(ka[rr], s4.w, wk4[3]);
            fma4(va[rr], s4.x, wv4[0]); fma4(va[rr], s4.y, wv4[1]);
            fma4(va[rr], s4.z, wv4[2]); fma4(va[rr], s4.w, wv4[3]);
        }
    }

    #pragma unroll
    for (int rr = 0; rr < 4; ++rr) {
        long row = row0 + rl * 4 + rr;
        float4 e4;
        e4.x = __expf(ka[rr].x); e4.y = __expf(ka[rr].y);
        e4.z = __expf(ka[rr].z); e4.w = __expf(ka[rr].w);
        float4 ev;
        ev.x = e4.x * va[rr].x; ev.y = e4.y * va[rr].y;
        ev.z = e4.z * va[rr].z; ev.w = e4.w * va[rr].w;
        *(float4*)(ek + row * D + dq * 4) = e4;
        *(float4*)(ekv + row * D + dq * 4) = ev;
    }
}

// ---------------------------------------------------------------------------
// K2: qsig = sigmoid(q1 @ Wqf^T + qlast @ Wql^T), kv-style (coalesced).
// block 256 = 32 dq x 8 rl; R2=16 rows/block -> 2 rows per thread.
// ---------------------------------------------------------------------------
#define R2 16
__global__ __launch_bounds__(256, 2) void q_kernel(
        const float* __restrict__ q1,
        const float* __restrict__ qlast,
        const float* __restrict__ wqfT,
        const float* __restrict__ wqlT,
        float* __restrict__ qsig) {
    __shared__ float sh1[R2][D];
    __shared__ float sh2[R2][D];
    const int t = threadIdx.x;
    const int dq = t & 31;
    const int rl = t >> 5;          // 0..7 -> rows rl*2, rl*2+1
    const long row0 = (long)blockIdx.x * R2;

    const float4* s1 = (const float4*)(q1 + row0 * D);
    const float4* s2 = (const float4*)(qlast + row0 * D);
    float4* d1 = (float4*)(&sh1[0][0]);
    float4* d2 = (float4*)(&sh2[0][0]);
    #pragma unroll
    for (int i = 0; i < (R2 * D / 4) / 256; ++i) {   // 2 iters
        d1[t + i * 256] = s1[t + i * 256];
        d2[t + i * 256] = s2[t + i * 256];
    }
    __syncthreads();

    float4 acc[2];
    acc[0] = make_float4(0.f, 0.f, 0.f, 0.f);
    acc[1] = make_float4(0.f, 0.f, 0.f, 0.f);

    const float* wfp = wqfT + dq * 4;
    const float* wlp = wqlT + dq * 4;
    #pragma unroll 4
    for (int e0 = 0; e0 < D; e0 += 4) {
        float4 wf4[4], wl4[4];
        #pragma unroll
        for (int ee = 0; ee < 4; ++ee) {
            wf4[ee] = *(const float4*)(wfp + (e0 + ee) * D);
            wl4[ee] = *(const float4*)(wlp + (e0 + ee) * D);
        }
        #pragma unroll
        for (int rr = 0; rr < 2; ++rr) {
            float4 a4 = *(const float4*)(&sh1[rl * 2 + rr][e0]);
            float4 b4 = *(const float4*)(&sh2[rl * 2 + rr][e0]);
            fma4(acc[rr], a4.x, wf4[0]); fma4(acc[rr], a4.y, wf4[1]);
            fma4(acc[rr], a4.z, wf4[2]); fma4(acc[rr], a4.w, wf4[3]);
            fma4(acc[rr], b4.x, wl4[0]); fma4(acc[rr], b4.y, wl4[1]);
            fma4(acc[rr], b4.z, wl4[2]); fma4(acc[rr], b4.w, wl4[3]);
        }
    }

    #pragma unroll
    for (int rr = 0; rr < 2; ++rr) {
        long row = row0 + rl * 2 + rr;
        float4 s;
        s.x = 1.0f / (1.0f + __expf(-acc[rr].x));
        s.y = 1.0f / (1.0f + __expf(-acc[rr].y));
        s.z = 1.0f / (1.0f + __expf(-acc[rr].z));
        s.w = 1.0f / (1.0f + __expf(-acc[rr].w));
        *(float4*)(qsig + row * D + dq * 4) = s;
    }
}

// ---------------------------------------------------------------------------
// K3a: partial num/den over an n-chunk (verified structure; NC up to 16).
// ---------------------------------------------------------------------------
#define PT 20
__global__ __launch_bounds__(128, 2) void aft_part_kernel(
        const float* __restrict__ cur_dist,
        const float* __restrict__ ninf,
        const float* __restrict__ ek,
        const float* __restrict__ ekv,
        const float* __restrict__ log_scale,
        const float* __restrict__ aft_alpha,
        float* __restrict__ pnum,
        float* __restrict__ pden,
        int NC, int L) {
    __shared__ float eb[128][PT];
    const int t = threadIdx.x;
    const int dq = t & 31;
    const int pl = t >> 5;
    const int c  = blockIdx.x % NC;
    const int pt = (blockIdx.x / NC) % (P / PT);
    const int b  = blockIdx.x / (NC * (P / PT));
    const int p0 = pt * PT;
    const int n_begin = c * L;
    const int n_end = min(N, n_begin + L);
    const float lsA = log_scale[0] * aft_alpha[0];

    float4 num[5], den[5];
    #pragma unroll
    for (int i = 0; i < 5; ++i) {
        num[i] = make_float4(0.f, 0.f, 0.f, 0.f);
        den[i] = make_float4(0.f, 0.f, 0.f, 0.f);
    }

    for (int n0 = n_begin; n0 < n_end; n0 += 128) {
        const int lim = min(128, n_end - n0);
        __syncthreads();
        if (t < lim) {
            int n = n0 + t;
            #pragma unroll
            for (int i = 0; i < PT; ++i) {
                long idx = ((long)b * P + p0 + i) * N + n;
                eb[t][i] = __expf(fmaf(-lsA, cur_dist[idx], ninf[idx]));
            }
        }
        __syncthreads();
        #pragma unroll 4
        for (int j = 0; j < lim; ++j) {
            long base = ((long)b * N + n0 + j) * D + dq * 4;
            float4 ekq = *(const float4*)(ek + base);
            float4 evq = *(const float4*)(ekv + base);
            float4 e4 = *(const float4*)(&eb[j][pl * 4]);
            float es = eb[j][16 + pl];
            fma4(num[0], e4.x, evq); fma4(den[0], e4.x, ekq);
            fma4(num[1], e4.y, evq); fma4(den[1], e4.y, ekq);
            fma4(num[2], e4.z, evq); fma4(den[2], e4.z, ekq);
            fma4(num[3], e4.w, evq); fma4(den[3], e4.w, ekq);
            fma4(num[4], es,   evq); fma4(den[4], es,   ekq);
        }
    }

    #pragma unroll
    for (int r = 0; r < 4; ++r) {
        int p = pl * 4 + r;
        long o = (((long)c * B + b) * P + p0 + p) * D + dq * 4;
        *(float4*)(pnum + o) = num[r];
        *(float4*)(pden + o) = den[r];
    }
    {
        int p = 16 + pl;
        long o = (((long)c * B + b) * P + p0 + p) * D + dq * 4;
        *(float4*)(pnum + o) = num[4];
        *(float4*)(pden + o) = den[4];
    }
}

// ---------------------------------------------------------------------------
// K3b: reduce chunks, aft = qsig * num / den.
// ---------------------------------------------------------------------------
__global__ void aft_reduce_kernel(const float* __restrict__ pnum,
                                  const float* __restrict__ pden,
                                  const float* __restrict__ qsig,
                                  float* __restrict__ aft,
                                  int NC) {
    const long i = (long)blockIdx.x * 256 + threadIdx.x;
    const long BPD = (long)B * P * D;
    float n = 0.f, d = 0.f;
    for (int c = 0; c < NC; ++c) {
        n += pnum[(long)c * BPD + i];
        d += pden[(long)c * BPD + i];
    }
    aft[i] = qsig[i] * n / d;
}

// ---------------------------------------------------------------------------
// K4: fused score + clip-tanh + softmax. aft rows staged in LDS; softmax
// batched to 4 barriers. 512 threads, thread owns n = 2t, 2t+1.
// ---------------------------------------------------------------------------
#define PT2 10
__global__ __launch_bounds__(512) void score_kernel(
        const float* __restrict__ aft,
        const float* __restrict__ nodesT,
        const float* __restrict__ cur_dist,
        const float* __restrict__ ninf,
        const float* __restrict__ log_scale,
        const float* __restrict__ dist_alpha,
        float* __restrict__ out) {
    __shared__ float sa[PT2][D];
    __shared__ float red[8][PT2];
    __shared__ float bmax[PT2];
    __shared__ float bsum[PT2];
    const int t = threadIdx.x;
    const int wid = t >> 6;
    const int pt = blockIdx.x % (P / PT2);
    const int b  = blockIdx.x / (P / PT2);
    const int p0 = pt * PT2;
    const float lsA = log_scale[0] * dist_alpha[0];

    // stage aft rows into LDS (coalesced float4)
    {
        const float4* src = (const float4*)(aft + ((long)b * P + p0) * D);
        float4* dst = (float4*)(&sa[0][0]);
        if (t < PT2 * D / 4) dst[t] = src[t];   // 320 items
    }
    __syncthreads();

    const int n0 = t * 2;
    const bool act = (n0 < N);
    const int ncl = act ? n0 : 0;
    const float* ntb = nodesT + (long)b * D * N;

    float2 acc[PT2];
    #pragma unroll
    for (int i = 0; i < PT2; ++i) acc[i] = make_float2(0.f, 0.f);

    #pragma unroll 4
    for (int e0 = 0; e0 < D; e0 += 4) {
        float2 x[4];
        #pragma unroll
        for (int ee = 0; ee < 4; ++ee)
            x[ee] = *(const float2*)(ntb + (long)(e0 + ee) * N + ncl);
        #pragma unroll
        for (int i = 0; i < PT2; ++i) {
            float4 a4 = *(const float4*)(&sa[i][e0]);  // uniform -> broadcast
            acc[i].x = fmaf(x[0].x, a4.x, acc[i].x);
            acc[i].x = fmaf(x[1].x, a4.y, acc[i].x);
            acc[i].x = fmaf(x[2].x, a4.z, acc[i].x);
            acc[i].x = fmaf(x[3].x, a4.w, acc[i].x);
            acc[i].y = fmaf(x[0].y, a4.x, acc[i].y);
            acc[i].y = fmaf(x[1].y, a4.y, acc[i].y);
            acc[i].y = fmaf(x[2].y, a4.z, acc[i].y);
            acc[i].y = fmaf(x[3].y, a4.w, acc[i].y);
        }
    }

    float2 sc[PT2];
    #pragma unroll
    for (int i = 0; i < PT2; ++i) {
        if (act) {
            long idx = ((long)b * P + p0 + i) * N + n0;
            float2 cd = *(const float2*)(cur_dist + idx);
            float2 nf = *(const float2*)(ninf + idx);
            float sx = fmaf(acc[i].x, SQRT_D_INV, -lsA * cd.x);
            float sy = fmaf(acc[i].y, SQRT_D_INV, -lsA * cd.y);
            float ax = fabsf(sx), ay = fabsf(sy);
            float rx = 1.f - 2.f / (__expf(2.f * ax) + 1.f);
            float ry = 1.f - 2.f / (__expf(2.f * ay) + 1.f);
            sc[i].x = CLIPV * copysignf(rx, sx) + nf.x;
            sc[i].y = CLIPV * copysignf(ry, sy) + nf.y;
        } else {
            sc[i].x = -INFINITY;
            sc[i].y = -INFINITY;
        }
    }

    // batched softmax: maxes for ALL i, one barrier round; then sums.
    #pragma unroll
    for (int i = 0; i < PT2; ++i) {
        float m = fmaxf(sc[i].x, sc[i].y);
        #pragma unroll
        for (int o = 1; o < 64; o <<= 1) m = fmaxf(m, __shfl_xor(m, o, 64));
        if ((t & 63) == 0) red[wid][i] = m;
    }
    __syncthreads();
    if (t < PT2) {
        float mm = red[0][t];
        #pragma unroll
        for (int w = 1; w < 8; ++w) mm = fmaxf(mm, red[w][t]);
        bmax[t] = mm;
    }
    __syncthreads();

    float2 ex[PT2];
    #pragma unroll
    for (int i = 0; i < PT2; ++i) {
        float m = bmax[i];
        ex[i].x = (sc[i].x > -1e30f) ? __expf(sc[i].x - m) : 0.f;
        ex[i].y = (sc[i].y > -1e30f) ? __expf(sc[i].y - m) : 0.f;
        float ssum = ex[i].x + ex[i].y;
        #pragma unroll
        for (int o = 1; o < 64; o <<= 1) ssum += __shfl_xor(ssum, o, 64);
        if ((t & 63) == 0) red[wid][i] = ssum;
    }
    __syncthreads();
    if (t < PT2) {
        float ss = red[0][t];
        #pragma unroll
        for (int w = 1; w < 8; ++w) ss += red[w][t];
        bsum[t] = ss;
    }
    __syncthreads();

    #pragma unroll
    for (int i = 0; i < PT2; ++i) {
        if (act) {
            float inv = 1.0f / bsum[i];
            long idx = ((long)b * P + p0 + i) * N + n0;
            *(float2*)(out + idx) = make_float2(ex[i].x * inv, ex[i].y * inv);
        }
    }
}

// ---------------------------------------------------------------------------
extern "C" void kernel_launch(void* const* d_in, const int* in_sizes, int n_in,
                              void* d_out, int out_size, void* d_ws, size_t ws_size,
                              hipStream_t stream) {
    const float* nodes      = (const float*)d_in[0];
    const float* q1         = (const float*)d_in[1];
    const float* qlast      = (const float*)d_in[2];
    const float* cur_dist   = (const float*)d_in[3];
    const float* ninf       = (const float*)d_in[4];
    const float* log_scale  = (const float*)d_in[5];
    const float* Wqf        = (const float*)d_in[6];
    const float* Wql        = (const float*)d_in[7];
    const float* Wk         = (const float*)d_in[8];
    const float* Wv         = (const float*)d_in[9];
    const float* dist_alpha = (const float*)d_in[10];
    const float* aft_alpha  = (const float*)d_in[11];
    float* out = (float*)d_out;

    const long BND = (long)B * N * D;
    const long BPD = (long)B * P * D;
    const long W2  = (long)D * D;

    float* ws     = (float*)d_ws;
    float* ek     = ws;
    float* ekv    = ek + BND;
    float* qsig   = ekv + BND;
    float* aft    = qsig + BPD;
    float* wkT    = aft + BPD;
    float* wvT    = wkT + W2;
    float* wqfT   = wvT + W2;
    float* wqlT   = wqfT + W2;
    float* nodesT = wqlT + W2;
    float* pnum   = nodesT + BND;

    long avail = (long)(ws_size / 4) - (3 * BND + 2 * BPD + 4 * W2);
    int NC = (int)(avail / (2 * BPD));
    if (NC < 1) NC = 1;
    if (NC > 16) NC = 16;
    int L = (N + NC - 1) / NC;
    float* pden = pnum + (long)NC * BPD;

    transpose_w4<<<D, D, 0, stream>>>(Wk, Wv, Wqf, Wql, wkT, wvT, wqfT, wqlT);
    transpose_nodes<<<B * ((N + TT - 1) / TT), 256, 0, stream>>>(nodes, nodesT);
    kv_kernel<<<(B * N) / R1, 256, 0, stream>>>(nodes, wkT, wvT, ek, ekv);
    q_kernel<<<(B * P) / R2, 256, 0, stream>>>(q1, qlast, wqfT, wqlT, qsig);
    aft_part_kernel<<<B * (P / PT) * NC, 128, 0, stream>>>(
        cur_dist, ninf, ek, ekv, log_scale, aft_alpha, pnum, pden, NC, L);
    aft_reduce_kernel<<<(int)(BPD / 256), 256, 0, stream>>>(pnum, pden, qsig, aft, NC);
    score_kernel<<<B * (P / PT2), 512, 0, stream>>>(
        aft, nodesT, cur_dist, ninf, log_scale, dist_alpha, out);
}